// Round 4
// baseline (123.941 us; speedup 1.0000x reference)
//
#include <hip/hip_runtime.h>
#include <hip/hip_bf16.h>
#include <stdint.h>
#include <stddef.h>

// ---------------------------------------------------------------------------
// MyConv2D fixed-point conv (Width=8), valid 3x3, NHWC, + bias + ReLU.
// R4: faithful m201-geometry port. BM=BN=256 BK=64, 512 thr, 8 waves (2Mx4N)
// each owning 128x64 (LDS:MFMA ratio 0.93). LDS [2buf][2half][128][64] per
// operand (128 KB). 4 phases/K-tile with 8/4/8/4 ds_read_b128 balance,
// region-recycling half-tile staging, counted vmcnt(4) (never 0 in loop),
// setprio around MFMA, XOR-swizzled LDS (0 conflicts, verified R2/R3).
// M=93312 -> 365 blocks (last half-padded: clamped staging, guarded stores).
// Exactness: quantized values a/256, |a|<=256 (bf16-exact); partial sums are
// integer multiples of 2^-16 << 2^24 -> fp32 MFMA accumulation exact.
// ---------------------------------------------------------------------------

typedef float  f32x4  __attribute__((ext_vector_type(4)));
typedef short  bf16x8 __attribute__((ext_vector_type(8)));

#define N_IMG 32
#define H_IN 56
#define W_IN 56
#define C_IN 128
#define F_OUT 256
#define OHW 54
#define M_TOTAL (N_IMG * OHW * OHW)   // 93312
#define BM 256
#define BN 256
#define BK 64
#define NBLK ((M_TOTAL + BM - 1) / BM) // 365

__device__ __forceinline__ unsigned short quant_to_bf16(float x) {
    float a = rintf(x * 256.0f);                 // half-to-even == jnp.round
    a = fminf(fmaxf(a, -256.0f), 256.0f);
    float q = a * 0.00390625f;                   // exact in bf16
    union { float f; unsigned int u; } cv; cv.f = q;
    return (unsigned short)(cv.u >> 16);
}

__device__ __forceinline__ void async_copy16(const unsigned short* g, unsigned short* l) {
    __builtin_amdgcn_global_load_lds(
        (const __attribute__((address_space(1))) unsigned int*)g,
        (__attribute__((address_space(3))) unsigned int*)l, 16, 0, 0);
}

__device__ __forceinline__ unsigned lds_off(const void* p) {
    return (unsigned)(uintptr_t)(__attribute__((address_space(3))) const void*)p;
}

__device__ __forceinline__ bf16x8 lds_read_b128(unsigned addr) {
    bf16x8 r;
    asm volatile("ds_read_b128 %0, %1" : "=v"(r) : "v"(addr));
    return r;
}

__global__ __launch_bounds__(256) void quant_x_kernel(
        const float* __restrict__ x, unsigned short* __restrict__ xq) {
    int i = (blockIdx.x * 256 + threadIdx.x) * 4;
    float4 v = *reinterpret_cast<const float4*>(x + i);
    ushort4 o;
    o.x = quant_to_bf16(v.x);
    o.y = quant_to_bf16(v.y);
    o.z = quant_to_bf16(v.z);
    o.w = quant_to_bf16(v.w);
    *reinterpret_cast<ushort4*>(xq + i) = o;
}

// w (3,3,128,256) -> wp[kk][f=256][c=128] bf16 (B^T, K-contiguous)
__global__ __launch_bounds__(256) void quant_w_kernel(
        const float* __restrict__ w, unsigned short* __restrict__ wp) {
    int idx = blockIdx.x * 256 + threadIdx.x;
    int c  = idx & 127;
    int f  = (idx >> 7) & 255;
    int kk = idx >> 15;
    wp[idx] = quant_to_bf16(w[(kk * C_IN + c) * F_OUT + f]);
}

__global__ __launch_bounds__(512, 2) void conv_kernel(
        const unsigned short* __restrict__ xq,   // [32][56][56][128] bf16
        const unsigned short* __restrict__ wp,   // [9][256][128] bf16
        const float* __restrict__ bias,          // [54][54][256]
        float* __restrict__ out)                 // [93312][256]
{
    // [buf][half][row 128][k 64] each => 32768 shorts = 64 KB per operand
    __shared__ __attribute__((aligned(16))) unsigned short Alds[32768];
    __shared__ __attribute__((aligned(16))) unsigned short Blds[32768];

    const int tid  = threadIdx.x;
    const int lane = tid & 63;
    const int wave = tid >> 6;
    const int wr   = wave >> 2;   // 0..1  (row half of block)
    const int wc   = wave & 3;    // 0..3  (64-col slice)

    // bijective XCD swizzle: nwg=365, q=45, r=5 (m204 variant)
    int bid = blockIdx.x;
    {
        int xc = bid & 7, l = bid >> 3;
        bid = (xc < 5 ? xc * 46 : 230 + (xc - 5) * 45) + l;
    }
    const int m0 = bid * BM;

    // ---- staging geometry: per half: chunk = r*512 + tid; row = 64r + tid>>3
    const int rowt = tid >> 3;                  // 0..63
    const int sw   = (tid & 7) ^ (rowt & 7);    // pre-swizzled source chunk
    const int dstc = (tid & ~63) * 8;           // wave-uniform dst (shorts)

    const unsigned short* aP[4];
#pragma unroll
    for (int h = 0; h < 2; ++h)
#pragma unroll
        for (int r = 0; r < 2; ++r) {
            int m = m0 + h * 128 + r * 64 + rowt;
            if (m > M_TOTAL - 1) m = M_TOTAL - 1;          // pad clamp
            int n_img = m / (OHW * OHW);
            int rem   = m % (OHW * OHW);
            int oh = rem / OHW, ow = rem % OHW;
            aP[h * 2 + r] = xq + (size_t)((n_img * H_IN + oh) * W_IN + ow) * C_IN + sw * 8;
        }
    const unsigned short* bP[4];
#pragma unroll
    for (int h = 0; h < 2; ++h)
#pragma unroll
        for (int r = 0; r < 2; ++r)
            bP[h * 2 + r] = wp + (size_t)(h * 128 + r * 64 + rowt) * C_IN + sw * 8;

    auto stageB = [&](int tt, int b) {
        int kk = tt >> 1, hk = tt & 1;
        int off = kk * (F_OUT * C_IN) + hk * 64;
#pragma unroll
        for (int h = 0; h < 2; ++h)
#pragma unroll
            for (int r = 0; r < 2; ++r)
                async_copy16(bP[h * 2 + r] + off,
                             Blds + (b * 2 + h) * 8192 + r * 4096 + dstc);
    };
    auto stageA = [&](int tt, int b) {
        int kk = tt >> 1, hk = tt & 1;
        int kh = (kk * 43) >> 7, kw = kk - 3 * kh;
        int off = (kh * W_IN + kw) * C_IN + hk * 64;
#pragma unroll
        for (int h = 0; h < 2; ++h)
#pragma unroll
            for (int r = 0; r < 2; ++r)
                async_copy16(aP[h * 2 + r] + off,
                             Alds + (b * 2 + h) * 8192 + r * 4096 + dstc);
    };

    // ---- fragment read geometry ----
    const int mr = lane & 15;
    const int lq = lane >> 4;
    unsigned ch[2];
    ch[0] = (unsigned)(((0 * 4 + lq) ^ (mr & 7)) * 16);
    ch[1] = (unsigned)(((1 * 4 + lq) ^ (mr & 7)) * 16);
    const unsigned aB0 = lds_off(Alds) + wr * 16384 + mr * 128;
    const unsigned bB0 = lds_off(Blds) + (wc >> 1) * 16384 + ((wc & 1) * 64 + mr) * 128;

    f32x4 acc[8][4];
#pragma unroll
    for (int i = 0; i < 8; ++i)
#pragma unroll
        for (int j = 0; j < 4; ++j) acc[i][j] = (f32x4)(0.0f);

    bf16x8 bfr[4][2];   // B fragments, carried across tiles (ni 0..3 x ks)

    // do one K-tile from buffer `buf`; optionally stage tile `stage_tt` and
    // prefetch next tile's B(ni 0,1); vm: -1 none, else s_waitcnt vmcnt(vm)
    auto do_tile = [&](int buf, int stage_tt, bool do_stage, bool read_next, int vm) {
        const unsigned ab = aB0 + buf * 32768;
        const unsigned bb = bB0 + buf * 32768;
        bf16x8 af[4][2];
        // ---- ph1: read A qm=0 (8); MFMA q00 (uses prefetched bfr[0..1]) ----
#pragma unroll
        for (int mi = 0; mi < 4; ++mi)
#pragma unroll
            for (int ks = 0; ks < 2; ++ks)
                af[mi][ks] = lds_read_b128(ab + mi * 2048 + ch[ks]);
        __builtin_amdgcn_s_barrier();
        asm volatile("s_waitcnt lgkmcnt(0)" ::: "memory");
        __builtin_amdgcn_sched_barrier(0);
        __builtin_amdgcn_s_setprio(1);
#pragma unroll
        for (int mi = 0; mi < 4; ++mi)
#pragma unroll
            for (int ni = 0; ni < 2; ++ni)
#pragma unroll
                for (int ks = 0; ks < 2; ++ks)
                    acc[mi][ni] = __builtin_amdgcn_mfma_f32_16x16x32_bf16(
                        af[mi][ks], bfr[ni][ks], acc[mi][ni], 0, 0, 0);
        __builtin_amdgcn_s_setprio(0);
        __builtin_amdgcn_s_barrier();
        // ---- ph2: read B ni 2,3 (4); MFMA q01 ----
#pragma unroll
        for (int ni = 0; ni < 2; ++ni)
#pragma unroll
            for (int ks = 0; ks < 2; ++ks)
                bfr[2 + ni][ks] = lds_read_b128(bb + (2 + ni) * 2048 + ch[ks]);
        __builtin_amdgcn_s_barrier();
        asm volatile("s_waitcnt lgkmcnt(0)" ::: "memory");
        __builtin_amdgcn_sched_barrier(0);
        __builtin_amdgcn_s_setprio(1);
#pragma unroll
        for (int mi = 0; mi < 4; ++mi)
#pragma unroll
            for (int ni = 0; ni < 2; ++ni)
#pragma unroll
                for (int ks = 0; ks < 2; ++ks)
                    acc[mi][2 + ni] = __builtin_amdgcn_mfma_f32_16x16x32_bf16(
                        af[mi][ks], bfr[2 + ni][ks], acc[mi][2 + ni], 0, 0, 0);
        __builtin_amdgcn_s_setprio(0);
        __builtin_amdgcn_s_barrier();
        // ---- ph3: read A qm=1 (8, reuse regs); stage B' (B regions free) ----
#pragma unroll
        for (int mi = 0; mi < 4; ++mi)
#pragma unroll
            for (int ks = 0; ks < 2; ++ks)
                af[mi][ks] = lds_read_b128(ab + 8192 + mi * 2048 + ch[ks]);
        if (do_stage) stageB(stage_tt, buf);
        __builtin_amdgcn_s_barrier();
        asm volatile("s_waitcnt lgkmcnt(0)" ::: "memory");
        __builtin_amdgcn_sched_barrier(0);
        __builtin_amdgcn_s_setprio(1);
#pragma unroll
        for (int mi = 0; mi < 4; ++mi)
#pragma unroll
            for (int ni = 0; ni < 2; ++ni)
#pragma unroll
                for (int ks = 0; ks < 2; ++ks)
                    acc[4 + mi][ni] = __builtin_amdgcn_mfma_f32_16x16x32_bf16(
                        af[mi][ks], bfr[ni][ks], acc[4 + mi][ni], 0, 0, 0);
        __builtin_amdgcn_s_setprio(0);
        __builtin_amdgcn_s_barrier();
        // ---- ph4: vmcnt; prefetch next-tile B ni 0,1; stage A'; MFMA q11 ----
        if (vm == 4)      asm volatile("s_waitcnt vmcnt(4)" ::: "memory");
        else if (vm == 0) asm volatile("s_waitcnt vmcnt(0)" ::: "memory");
        if (vm >= 0) __builtin_amdgcn_s_barrier();
        if (read_next) {
            const unsigned bbn = bB0 + (buf ^ 1) * 32768;
#pragma unroll
            for (int ni = 0; ni < 2; ++ni)
#pragma unroll
                for (int ks = 0; ks < 2; ++ks)
                    bfr[ni][ks] = lds_read_b128(bbn + ni * 2048 + ch[ks]);
        }
        if (do_stage) stageA(stage_tt, buf);
        __builtin_amdgcn_s_setprio(1);
#pragma unroll
        for (int mi = 0; mi < 4; ++mi)
#pragma unroll
            for (int ni = 0; ni < 2; ++ni)
#pragma unroll
                for (int ks = 0; ks < 2; ++ks)
                    acc[4 + mi][2 + ni] = __builtin_amdgcn_mfma_f32_16x16x32_bf16(
                        af[mi][ks], bfr[2 + ni][ks], acc[4 + mi][2 + ni], 0, 0, 0);
        __builtin_amdgcn_s_setprio(0);
        __builtin_amdgcn_s_barrier();
    };

    // ---- prologue: stage tiles 0,1; wait tile 0; preload its B ni 0,1 ----
    stageB(0, 0); stageA(0, 0);
    stageB(1, 1); stageA(1, 1);
    asm volatile("s_waitcnt vmcnt(8)" ::: "memory");
    __builtin_amdgcn_s_barrier();
#pragma unroll
    for (int ni = 0; ni < 2; ++ni)
#pragma unroll
        for (int ks = 0; ks < 2; ++ks)
            bfr[ni][ks] = lds_read_b128(bB0 + ni * 2048 + ch[ks]);

    // ---- main loop: tiles 0..15 steady state (vmcnt(4), never drained) ----
#pragma unroll 1
    for (int tp = 0; tp < 8; ++tp) {
        do_tile(0, 2 * tp + 2, true, true, 4);
        do_tile(1, 2 * tp + 3, true, true, 4);
    }
    do_tile(0, 0, false, true, 0);    // t=16: full drain once (near end)
    do_tile(1, 0, false, false, -1);  // t=17: last tile

    // ---- epilogue: quantize, bias, ReLU, guarded stores ----
#pragma unroll
    for (int mi = 0; mi < 8; ++mi) {
#pragma unroll
        for (int rr = 0; rr < 4; ++rr) {
            const int m = m0 + wr * 128 + (mi >> 2) * 64 + (mi & 3) * 16 + lq * 4 + rr;
            if (m < M_TOTAL) {
                const float* brow = bias + (size_t)(m % (OHW * OHW)) * F_OUT;
                float* orow = out + (size_t)m * F_OUT;
#pragma unroll
                for (int ni = 0; ni < 4; ++ni) {
                    const int fc = wc * 64 + ni * 16 + mr;
                    float v = acc[mi][ni][rr];
                    float t = rintf(v * 256.0f);
                    t = fminf(fmaxf(t, -256.0f), 256.0f);
                    float o = t * 0.00390625f + brow[fc];
                    orow[fc] = fmaxf(o, 0.0f);
                }
            }
        }
    }
}

extern "C" void kernel_launch(void* const* d_in, const int* in_sizes, int n_in,
                              void* d_out, int out_size, void* d_ws, size_t ws_size,
                              hipStream_t stream) {
    (void)in_sizes; (void)n_in; (void)out_size;
    const float* x    = (const float*)d_in[0];
    const float* w    = (const float*)d_in[1];
    const float* bias = (const float*)d_in[2];
    float* out        = (float*)d_out;

    const size_t x_elems = (size_t)N_IMG * H_IN * W_IN * C_IN;
    const size_t w_elems = (size_t)9 * F_OUT * C_IN;
    const size_t xq_bytes = x_elems * sizeof(unsigned short);
    const size_t need = xq_bytes + w_elems * sizeof(unsigned short);
    if (ws_size < need) return;

    unsigned short* xq = (unsigned short*)d_ws;
    unsigned short* wp = (unsigned short*)((char*)d_ws + xq_bytes);

    quant_x_kernel<<<(int)(x_elems / (256 * 4)), 256, 0, stream>>>(x, xq);
    quant_w_kernel<<<(int)(w_elems / 256), 256, 0, stream>>>(w, wp);
    conv_kernel<<<NBLK, 512, 0, stream>>>(xq, wp, bias, out);
}

// Round 5
// 96.003 us; speedup vs baseline: 1.2910x; 1.2910x over previous
//
#include <hip/hip_runtime.h>
#include <hip/hip_bf16.h>
#include <stdint.h>
#include <stddef.h>

// ---------------------------------------------------------------------------
// MyConv2D fixed-point conv (Width=8), valid 3x3, NHWC, + bias + ReLU.
// R5: R2 geometry (BM=128 BN=128 BK=64, 256 thr, 4 waves 2x2, 64x64/wave,
// proven 671 TF) + T3-minimum 2-phase prefetch: double-buffered LDS (64 KB,
// 2 blocks/CU), stage tile t+1 (global_load_lds w=16) overlapped with
// compute of tile t, ONE __syncthreads per tile (its implicit vmcnt(0) is
// the counted wait). XOR-swizzled LDS both-sides (0 conflicts, verified).
// Exactness: quantized values a/256, |a|<=256 (bf16-exact); partial sums are
// integer multiples of 2^-16 << 2^24 -> fp32 MFMA accumulation exact.
// ---------------------------------------------------------------------------

typedef float  f32x4  __attribute__((ext_vector_type(4)));
typedef short  bf16x8 __attribute__((ext_vector_type(8)));

#define N_IMG 32
#define H_IN 56
#define W_IN 56
#define C_IN 128
#define F_OUT 256
#define OHW 54
#define M_TOTAL (N_IMG * OHW * OHW)   // 93312 = 729 * 128
#define BM 128
#define BN 128
#define BK 64

__device__ __forceinline__ unsigned short quant_to_bf16(float x) {
    float a = rintf(x * 256.0f);                 // half-to-even == jnp.round
    a = fminf(fmaxf(a, -256.0f), 256.0f);
    float q = a * 0.00390625f;                   // exact in bf16
    union { float f; unsigned int u; } cv; cv.f = q;
    return (unsigned short)(cv.u >> 16);
}

__device__ __forceinline__ void async_copy16(const unsigned short* g, unsigned short* l) {
    __builtin_amdgcn_global_load_lds(
        (const __attribute__((address_space(1))) unsigned int*)g,
        (__attribute__((address_space(3))) unsigned int*)l, 16, 0, 0);
}

__global__ __launch_bounds__(256) void quant_x_kernel(
        const float* __restrict__ x, unsigned short* __restrict__ xq) {
    int i = (blockIdx.x * 256 + threadIdx.x) * 4;
    float4 v = *reinterpret_cast<const float4*>(x + i);
    ushort4 o;
    o.x = quant_to_bf16(v.x);
    o.y = quant_to_bf16(v.y);
    o.z = quant_to_bf16(v.z);
    o.w = quant_to_bf16(v.w);
    *reinterpret_cast<ushort4*>(xq + i) = o;
}

// w (3,3,128,256) -> wp[kk][f=256][c=128] bf16 (B^T, K-contiguous)
__global__ __launch_bounds__(256) void quant_w_kernel(
        const float* __restrict__ w, unsigned short* __restrict__ wp) {
    int idx = blockIdx.x * 256 + threadIdx.x;
    int c  = idx & 127;
    int f  = (idx >> 7) & 255;
    int kk = idx >> 15;
    wp[idx] = quant_to_bf16(w[(kk * C_IN + c) * F_OUT + f]);
}

__global__ __launch_bounds__(256, 2) void conv_kernel(
        const unsigned short* __restrict__ xq,   // [32][56][56][128] bf16
        const unsigned short* __restrict__ wp,   // [9][256][128] bf16
        const float* __restrict__ bias,          // [54][54][256]
        float* __restrict__ out)                 // [93312][256]
{
    __shared__ __attribute__((aligned(16))) unsigned short Alds[2][BM * BK]; // 32 KB
    __shared__ __attribute__((aligned(16))) unsigned short Blds[2][BN * BK]; // 32 KB

    const int tid  = threadIdx.x;
    const int wave = tid >> 6;
    const int lane = tid & 63;
    const int bid  = blockIdx.x;
    const int mb   = bid >> 1;      // consecutive bid pairs share A -> same XCD
    const int nb   = bid & 1;
    const int m0   = mb * BM;
    const int wr   = wave >> 1;     // 0..1
    const int wc   = wave & 1;      // 0..1

    // ---- staging geometry: chunk = r*256 + tid; row = (tid>>3) + 32r ----
    const int row0 = tid >> 3;                    // 0..31
    const int sw   = (tid & 7) ^ (row0 & 7);      // pre-swizzled source chunk
    const int dstc = (tid & ~63) * 8;             // wave-uniform dst (shorts)

    const unsigned short* a_base[4];
#pragma unroll
    for (int r = 0; r < 4; ++r) {
        int m = m0 + row0 + 32 * r;
        int n_img = m / (OHW * OHW);
        int rem   = m % (OHW * OHW);
        int oh = rem / OHW, ow = rem % OHW;
        a_base[r] = xq + (size_t)((n_img * H_IN + oh) * W_IN + ow) * C_IN + sw * 8;
    }
    const unsigned short* b_base[4];
#pragma unroll
    for (int r = 0; r < 4; ++r)
        b_base[r] = wp + (size_t)(nb * BN + row0 + 32 * r) * C_IN + sw * 8;

    // stage tile t into buffer (Ab,Bb): 4 A-gloads + 4 B-gloads (16B/lane)
    auto stage = [&](int t, unsigned short* Ab, unsigned short* Bb) {
        int kk = t >> 1, hf = t & 1;
        int kh = (kk * 43) >> 7, kw = kk - 3 * kh;   // kk/3, kk%3 for kk<=8
        int aoff = (kh * W_IN + kw) * C_IN + hf * 64;
        int boff = kk * (F_OUT * C_IN) + hf * 64;
#pragma unroll
        for (int r = 0; r < 4; ++r)
            async_copy16(a_base[r] + aoff, Ab + r * 2048 + dstc);
#pragma unroll
        for (int r = 0; r < 4; ++r)
            async_copy16(b_base[r] + boff, Bb + r * 2048 + dstc);
    };

    // ---- fragment read geometry ----
    const int mr = lane & 15;
    const int lq = lane >> 4;

    f32x4 acc[4][4];
#pragma unroll
    for (int i = 0; i < 4; ++i)
#pragma unroll
        for (int j = 0; j < 4; ++j) acc[i][j] = (f32x4)(0.0f);

    auto compute = [&](const unsigned short* Ab, const unsigned short* Bb) {
#pragma unroll
        for (int ks = 0; ks < 2; ++ks) {
            const int ch = (((ks * 4 + lq) ^ (mr & 7)) * 8);
            bf16x8 af[4], bfr[4];
#pragma unroll
            for (int mi = 0; mi < 4; ++mi)
                af[mi] = *reinterpret_cast<const bf16x8*>(
                    Ab + (wr * 64 + mi * 16 + mr) * BK + ch);
#pragma unroll
            for (int ni = 0; ni < 4; ++ni)
                bfr[ni] = *reinterpret_cast<const bf16x8*>(
                    Bb + (wc * 64 + ni * 16 + mr) * BK + ch);
#pragma unroll
            for (int mi = 0; mi < 4; ++mi)
#pragma unroll
                for (int ni = 0; ni < 4; ++ni)
                    acc[mi][ni] = __builtin_amdgcn_mfma_f32_16x16x32_bf16(
                        af[mi], bfr[ni], acc[mi][ni], 0, 0, 0);
        }
    };

    // ---- prologue ----
    stage(0, Alds[0], Blds[0]);
    __syncthreads();                       // drain tile-0 loads

    // ---- 2-phase main loop: stage(t+1) overlapped with compute(t) ----
#pragma unroll 1
    for (int tp = 0; tp < 8; ++tp) {
        stage(2 * tp + 1, Alds[1], Blds[1]);
        compute(Alds[0], Blds[0]);
        __syncthreads();                   // vmcnt(0): waits only tile t+1 loads
        stage(2 * tp + 2, Alds[0], Blds[0]);
        compute(Alds[1], Blds[1]);
        __syncthreads();
    }
    stage(17, Alds[1], Blds[1]);
    compute(Alds[0], Blds[0]);
    __syncthreads();
    compute(Alds[1], Blds[1]);             // last tile, no trailing barrier

    // ---- epilogue: quantize, bias, ReLU ----
    const int fcol0 = nb * BN + wc * 64 + mr;
#pragma unroll
    for (int mi = 0; mi < 4; ++mi) {
#pragma unroll
        for (int rr = 0; rr < 4; ++rr) {
            const int m = m0 + wr * 64 + mi * 16 + lq * 4 + rr;
            const float* brow = bias + (size_t)(m % (OHW * OHW)) * F_OUT;
            float* orow = out + (size_t)m * F_OUT;
#pragma unroll
            for (int ni = 0; ni < 4; ++ni) {
                float v = acc[mi][ni][rr];
                float t = rintf(v * 256.0f);
                t = fminf(fmaxf(t, -256.0f), 256.0f);
                float o = t * 0.00390625f + brow[fcol0 + ni * 16];
                orow[fcol0 + ni * 16] = fmaxf(o, 0.0f);
            }
        }
    }
}

extern "C" void kernel_launch(void* const* d_in, const int* in_sizes, int n_in,
                              void* d_out, int out_size, void* d_ws, size_t ws_size,
                              hipStream_t stream) {
    (void)in_sizes; (void)n_in; (void)out_size;
    const float* x    = (const float*)d_in[0];
    const float* w    = (const float*)d_in[1];
    const float* bias = (const float*)d_in[2];
    float* out        = (float*)d_out;

    const size_t x_elems = (size_t)N_IMG * H_IN * W_IN * C_IN;
    const size_t w_elems = (size_t)9 * F_OUT * C_IN;
    const size_t xq_bytes = x_elems * sizeof(unsigned short);
    const size_t need = xq_bytes + w_elems * sizeof(unsigned short);
    if (ws_size < need) return;

    unsigned short* xq = (unsigned short*)d_ws;
    unsigned short* wp = (unsigned short*)((char*)d_ws + xq_bytes);

    quant_x_kernel<<<(int)(x_elems / (256 * 4)), 256, 0, stream>>>(x, xq);
    quant_w_kernel<<<(int)(w_elems / 256), 256, 0, stream>>>(w, wp);
    conv_kernel<<<(M_TOTAL / BM) * 2, 256, 0, stream>>>(xq, wp, bias, out);
}

// Round 6
// 86.853 us; speedup vs baseline: 1.4270x; 1.1054x over previous
//
#include <hip/hip_runtime.h>
#include <hip/hip_bf16.h>
#include <stdint.h>
#include <stddef.h>

// ---------------------------------------------------------------------------
// MyConv2D fixed-point conv (Width=8), valid 3x3, NHWC, + bias + ReLU.
// R6: R5 skeleton (BM=128 BN=128 BK=64, 256 thr, 4 waves 2x2, 64x64/wave,
// 2-phase prefetch, 1 barrier/tile) with B REMOVED FROM LDS:
//  - A: LDS double-buffered (32 KB), global_load_lds w16, XOR swizzle
//    (0 conflicts, verified R2/R5).
//  - B: direct global->VGPR, double-buffered in registers one tile ahead.
//    quant_w writes B in per-lane FRAGMENT ORDER wpf[kk][hf][ks][g][lane][8]
//    so each wave frag-load is 1 KB contiguous (perfectly coalesced, L2-hot:
//    B total = 576 KB).
// LDS traffic per tile-pair: 192 KB -> 96 KB (below MFMA budget); B rides the
// otherwise-idle VMEM/L2 pipe.
// Exactness: quantized values a/256, |a|<=256 (bf16-exact); partial sums are
// integer multiples of 2^-16 << 2^24 -> fp32 MFMA accumulation exact.
// ---------------------------------------------------------------------------

typedef float  f32x4  __attribute__((ext_vector_type(4)));
typedef short  bf16x8 __attribute__((ext_vector_type(8)));

#define N_IMG 32
#define H_IN 56
#define W_IN 56
#define C_IN 128
#define F_OUT 256
#define OHW 54
#define M_TOTAL (N_IMG * OHW * OHW)   // 93312 = 729 * 128
#define BM 128
#define BN 128
#define BK 64

__device__ __forceinline__ unsigned short quant_to_bf16(float x) {
    float a = rintf(x * 256.0f);                 // half-to-even == jnp.round
    a = fminf(fmaxf(a, -256.0f), 256.0f);
    float q = a * 0.00390625f;                   // exact in bf16
    union { float f; unsigned int u; } cv; cv.f = q;
    return (unsigned short)(cv.u >> 16);
}

__device__ __forceinline__ void async_copy16(const unsigned short* g, unsigned short* l) {
    __builtin_amdgcn_global_load_lds(
        (const __attribute__((address_space(1))) unsigned int*)g,
        (__attribute__((address_space(3))) unsigned int*)l, 16, 0, 0);
}

__global__ __launch_bounds__(256) void quant_x_kernel(
        const float* __restrict__ x, unsigned short* __restrict__ xq) {
    int i = (blockIdx.x * 256 + threadIdx.x) * 4;
    float4 v = *reinterpret_cast<const float4*>(x + i);
    ushort4 o;
    o.x = quant_to_bf16(v.x);
    o.y = quant_to_bf16(v.y);
    o.z = quant_to_bf16(v.z);
    o.w = quant_to_bf16(v.w);
    *reinterpret_cast<ushort4*>(xq + i) = o;
}

// w (3,3,128,256) -> wpf in MFMA-B fragment order:
//   idx = ((((kk*2 + hf)*2 + ks)*16 + g)*64 + l)*8 + j
//   element: f = g*16 + (l&15); c = hf*64 + ks*32 + (l>>4)*8 + j; tap kk
// A wave's B-frag (g fixed) is then 64 lanes x 16 B contiguous = 1 KB.
__global__ __launch_bounds__(256) void quant_w_kernel(
        const float* __restrict__ w, unsigned short* __restrict__ wpf) {
    int idx = blockIdx.x * 256 + threadIdx.x;     // 294912 total
    int j  = idx & 7;
    int l  = (idx >> 3) & 63;
    int g  = (idx >> 9) & 15;
    int ks = (idx >> 13) & 1;
    int hf = (idx >> 14) & 1;
    int kk = idx >> 15;
    int f  = g * 16 + (l & 15);
    int c  = hf * 64 + ks * 32 + (l >> 4) * 8 + j;
    wpf[idx] = quant_to_bf16(w[(kk * C_IN + c) * F_OUT + f]);
}

__global__ __launch_bounds__(256, 2) void conv_kernel(
        const unsigned short* __restrict__ xq,   // [32][56][56][128] bf16
        const unsigned short* __restrict__ wpf,  // fragment-ordered B
        const float* __restrict__ bias,          // [54][54][256]
        float* __restrict__ out)                 // [93312][256]
{
    __shared__ __attribute__((aligned(16))) unsigned short Alds[2][BM * BK]; // 32 KB

    const int tid  = threadIdx.x;
    const int wave = tid >> 6;
    const int lane = tid & 63;
    const int bid  = blockIdx.x;
    const int mb   = bid >> 1;      // consecutive bid pairs share A rows
    const int nb   = bid & 1;
    const int m0   = mb * BM;
    const int wr   = wave >> 1;     // 0..1
    const int wc   = wave & 1;      // 0..1

    // ---- A staging geometry: chunk = r*256 + tid; row = (tid>>3) + 32r ----
    const int row0 = tid >> 3;                    // 0..31
    const int sw   = (tid & 7) ^ (row0 & 7);      // pre-swizzled source chunk
    const int dstc = (tid & ~63) * 8;             // wave-uniform dst (shorts)

    const unsigned short* a_base[4];
#pragma unroll
    for (int r = 0; r < 4; ++r) {
        int m = m0 + row0 + 32 * r;
        int n_img = m / (OHW * OHW);
        int rem   = m % (OHW * OHW);
        int oh = rem / OHW, ow = rem % OHW;
        a_base[r] = xq + (size_t)((n_img * H_IN + oh) * W_IN + ow) * C_IN + sw * 8;
    }

    // stage A tile t into buffer Ab: 4 gloads (16B/lane)
    auto stageA = [&](int t, unsigned short* Ab) {
        int kk = t >> 1, hf = t & 1;
        int kh = (kk * 43) >> 7, kw = kk - 3 * kh;   // kk/3, kk%3 for kk<=8
        int aoff = (kh * W_IN + kw) * C_IN + hf * 64;
#pragma unroll
        for (int r = 0; r < 4; ++r)
            async_copy16(a_base[r] + aoff, Ab + r * 2048 + dstc);
    };

    // ---- B fragment loads: contiguous 1 KB per wave per (ni,ks) ----
    // ptr = wpf + t*16384 + ks*8192 + (nb*8 + wc*4 + ni)*512 + lane*8
    const unsigned short* b_base = wpf + (size_t)(nb * 8 + wc * 4) * 512 + lane * 8;

    bf16x8 bregA[4][2], bregB[4][2];   // two named buffers (rule #20)
    auto loadB_A = [&](int t) {
#pragma unroll
        for (int ni = 0; ni < 4; ++ni)
#pragma unroll
            for (int ks = 0; ks < 2; ++ks)
                bregA[ni][ks] = *reinterpret_cast<const bf16x8*>(
                    b_base + t * 16384 + ks * 8192 + ni * 512);
    };
    auto loadB_B = [&](int t) {
#pragma unroll
        for (int ni = 0; ni < 4; ++ni)
#pragma unroll
            for (int ks = 0; ks < 2; ++ks)
                bregB[ni][ks] = *reinterpret_cast<const bf16x8*>(
                    b_base + t * 16384 + ks * 8192 + ni * 512);
    };

    // ---- fragment read geometry (A from LDS, swizzled) ----
    const int mr = lane & 15;
    const int lq = lane >> 4;

    f32x4 acc[4][4];
#pragma unroll
    for (int i = 0; i < 4; ++i)
#pragma unroll
        for (int j = 0; j < 4; ++j) acc[i][j] = (f32x4)(0.0f);

    auto computeA = [&](const unsigned short* Ab) {   // uses bregA
#pragma unroll
        for (int ks = 0; ks < 2; ++ks) {
            const int ch = (((ks * 4 + lq) ^ (mr & 7)) * 8);
            bf16x8 af[4];
#pragma unroll
            for (int mi = 0; mi < 4; ++mi)
                af[mi] = *reinterpret_cast<const bf16x8*>(
                    Ab + (wr * 64 + mi * 16 + mr) * BK + ch);
#pragma unroll
            for (int mi = 0; mi < 4; ++mi)
#pragma unroll
                for (int ni = 0; ni < 4; ++ni)
                    acc[mi][ni] = __builtin_amdgcn_mfma_f32_16x16x32_bf16(
                        af[mi], bregA[ni][ks], acc[mi][ni], 0, 0, 0);
        }
    };
    auto computeB = [&](const unsigned short* Ab) {   // uses bregB
#pragma unroll
        for (int ks = 0; ks < 2; ++ks) {
            const int ch = (((ks * 4 + lq) ^ (mr & 7)) * 8);
            bf16x8 af[4];
#pragma unroll
            for (int mi = 0; mi < 4; ++mi)
                af[mi] = *reinterpret_cast<const bf16x8*>(
                    Ab + (wr * 64 + mi * 16 + mr) * BK + ch);
#pragma unroll
            for (int mi = 0; mi < 4; ++mi)
#pragma unroll
                for (int ni = 0; ni < 4; ++ni)
                    acc[mi][ni] = __builtin_amdgcn_mfma_f32_16x16x32_bf16(
                        af[mi], bregB[ni][ks], acc[mi][ni], 0, 0, 0);
        }
    };

    // ---- prologue ----
    stageA(0, Alds[0]);
    loadB_A(0);
    __syncthreads();                       // drain tile-0 A loads

    // ---- 2-phase main loop: stage/load(t+1) overlapped with compute(t) ----
#pragma unroll 1
    for (int tp = 0; tp < 8; ++tp) {
        stageA(2 * tp + 1, Alds[1]);
        loadB_B(2 * tp + 1);
        computeA(Alds[0]);
        __syncthreads();                   // implicit vmcnt(0): t+1 data landed
        stageA(2 * tp + 2, Alds[0]);
        loadB_A(2 * tp + 2);
        computeB(Alds[1]);
        __syncthreads();
    }
    stageA(17, Alds[1]);
    loadB_B(17);
    computeA(Alds[0]);
    __syncthreads();
    computeB(Alds[1]);                     // last tile

    // ---- epilogue: quantize, bias, ReLU ----
    const int fcol0 = nb * BN + wc * 64 + mr;
#pragma unroll
    for (int mi = 0; mi < 4; ++mi) {
#pragma unroll
        for (int rr = 0; rr < 4; ++rr) {
            const int m = m0 + wr * 64 + mi * 16 + lq * 4 + rr;
            const float* brow = bias + (size_t)(m % (OHW * OHW)) * F_OUT;
            float* orow = out + (size_t)m * F_OUT;
#pragma unroll
            for (int ni = 0; ni < 4; ++ni) {
                float v = acc[mi][ni][rr];
                float t = rintf(v * 256.0f);
                t = fminf(fmaxf(t, -256.0f), 256.0f);
                float o = t * 0.00390625f + brow[fcol0 + ni * 16];
                orow[fcol0 + ni * 16] = fmaxf(o, 0.0f);
            }
        }
    }
}

extern "C" void kernel_launch(void* const* d_in, const int* in_sizes, int n_in,
                              void* d_out, int out_size, void* d_ws, size_t ws_size,
                              hipStream_t stream) {
    (void)in_sizes; (void)n_in; (void)out_size;
    const float* x    = (const float*)d_in[0];
    const float* w    = (const float*)d_in[1];
    const float* bias = (const float*)d_in[2];
    float* out        = (float*)d_out;

    const size_t x_elems = (size_t)N_IMG * H_IN * W_IN * C_IN;
    const size_t w_elems = (size_t)9 * F_OUT * C_IN;
    const size_t xq_bytes = x_elems * sizeof(unsigned short);  // 16B-aligned
    const size_t need = xq_bytes + w_elems * sizeof(unsigned short);
    if (ws_size < need) return;

    unsigned short* xq  = (unsigned short*)d_ws;
    unsigned short* wpf = (unsigned short*)((char*)d_ws + xq_bytes);

    quant_x_kernel<<<(int)(x_elems / (256 * 4)), 256, 0, stream>>>(x, xq);
    quant_w_kernel<<<(int)(w_elems / 256), 256, 0, stream>>>(w, wpf);
    conv_kernel<<<(M_TOTAL / BM) * 2, 256, 0, stream>>>(xq, wpf, bias, out);
}